// Round 3
// baseline (422.309 us; speedup 1.0000x reference)
//
#include <hip/hip_runtime.h>
#include <hip/hip_bf16.h>
#include <stdint.h>

// QuantizedLinear: out_f32[512,16384] = x_f32[512,4096] @ (qw_i32 * scales)^T + bias
// dtypes (verified round 3): x fp32, qw int32, scales fp32, bias fp32, out fp32.
//
// Round-10: same pipeline as round-8/9 (which never ran: container failed 2x2).
// Only change: the main loop's "#pragma unroll 2" is HAND-EXPANDED into an
// explicit kb+=2 loop with two macro bodies carrying compile-time CUR=0/1.
// Rationale: discriminate "hipcc pathological compile hang on the unrolled
// restructured loop" (-> container timeout) from generic infra flakiness,
// while preserving static indexing of sB[] and the A register double-buffer
// (runtime-indexed ext_vector arrays would go to scratch).
//
// Round-8 design (unchanged semantics):
//  - qw pipeline one iter deeper: iter kb dequants slab kb+1 (qv issued a
//    full iteration ago) and ds_writes it EARLY into the idle buffer (safe:
//    that buffer's readers passed the previous end-of-iter barrier).
//  - A(kb+1) loads issued BEFORE qv(kb+2): in-order vmcnt retirement means
//    compute never waits behind the qw wire.
//  - single lgkm-only barrier per iter, at the END; none after the last.
//  - register diet: j-paired B-fragment reads, transient dequant result.
// Unchanged: grid 256 x 1024, tiles (BM=512,BN=64,BK=128), fragment-order
// swizzled LDS (conflict-free), packed-x prepass, epilogue.

#define MM 512
#define NN 16384
#define KK 4096
#define BN 64
#define BK 128
#define NKB (KK / BK)   // 32

typedef __bf16 bf16x8 __attribute__((ext_vector_type(8)));
typedef float floatx4 __attribute__((ext_vector_type(4)));

__device__ __forceinline__ void barrier_nodrain() {
    // LDS handoff needs lgkmcnt(0); deliberately NO vmcnt drain.
    asm volatile("s_waitcnt lgkmcnt(0)\n\ts_barrier" ::: "memory");
}

__device__ __forceinline__ unsigned int pk_bf16_rtn(float lo, float hi) {
    __hip_bfloat162 h = __float22bfloat162_rn(float2{lo, hi});
    return *reinterpret_cast<unsigned int*>(&h);
}

__device__ __forceinline__ uint4 deq8(const int4 q0, const int4 q1, const float s) {
    uint4 u;
    u.x = pk_bf16_rtn((float)q0.x * s, (float)q0.y * s);
    u.y = pk_bf16_rtn((float)q0.z * s, (float)q0.w * s);
    u.z = pk_bf16_rtn((float)q1.x * s, (float)q1.y * s);
    u.w = pk_bf16_rtn((float)q1.z * s, (float)q1.w * s);
    return u;
}

// ---- prepass: x fp32 -> bf16, packed in MFMA A-fragment order ----
// xp element index: (((kb*4 + ks)*32 + mt)*64 + lane)*8,
//   holding x[mt*16 + (lane&15)][kb*128 + ks*32 + (lane>>4)*8 .. +8]
__global__ __launch_bounds__(256) void pack_x(const float* __restrict__ x,
                                              unsigned short* __restrict__ xp) {
    const int t    = blockIdx.x * 256 + threadIdx.x;   // 0..262143
    const int lane = t & 63;
    const int mt   = (t >> 6) & 31;
    const int ks   = (t >> 11) & 3;
    const int kb   = t >> 13;
    const int m    = mt * 16 + (lane & 15);
    const int k    = kb * 128 + ks * 32 + (lane >> 4) * 8;
    const float* px = x + (size_t)m * KK + k;
    const float4 a = *(const float4*)px;
    const float4 b = *(const float4*)(px + 4);
    uint4 o;
    o.x = pk_bf16_rtn(a.x, a.y);
    o.y = pk_bf16_rtn(a.z, a.w);
    o.z = pk_bf16_rtn(b.x, b.y);
    o.w = pk_bf16_rtn(b.z, b.w);
    *(uint4*)(xp + (size_t)t * 8) = o;   // fully coalesced 16B/thread
}

// One pipeline iteration. KB is a uniform runtime value; CUR is a literal so
// every sB[] / a[] index stays compile-time static.
#define GEMM_ITER(KB, CUR)                                                          \
    {                                                                               \
        const unsigned short* sb = sB[(CUR)];                                       \
        unsigned short* sbw      = sB[(CUR) ^ 1];                                   \
        if ((KB) + 1 < NKB) {                                                       \
            /* dequant slab KB+1 (qv issued one full iteration ago) + EARLY */      \
            /* LDS write; safe: buf[CUR^1] readers passed iter KB-1's barrier. */   \
            uint4 u = deq8(qv0, qv1, s);                                            \
            *(uint4*)(sbw + woff) = u;                                              \
            /* A(KB+1) issued FIRST in this iter's vmem queue */                    \
            if constexpr (PRE) {                                                    \
                const unsigned short* xpb =                                         \
                    xp + (size_t)((KB) + 1) * (4 * 32 * 64 * 8);                    \
                _Pragma("unroll")                                                   \
                for (int ks = 0; ks < 4; ++ks) {                                    \
                    const unsigned short* ap =                                      \
                        xpb + (size_t)((ks * 32 + w * 2) * 64 + lane) * 8;          \
                    a[(CUR) ^ 1][ks][0] = *(const bf16x8*)(ap);                     \
                    a[(CUR) ^ 1][ks][1] = *(const bf16x8*)(ap + 512);               \
                }                                                                   \
            }                                                                       \
        }                                                                           \
        if ((KB) + 2 < NKB) {                                                       \
            /* qw slab KB+2: issued last, consumed at iter KB+1's dequant */        \
            qv0 = *(const int4*)(qp + (size_t)((KB) + 2) * BK);                     \
            qv1 = *(const int4*)(qp + (size_t)((KB) + 2) * BK + 4);                 \
            s   = sp[(size_t)((KB) + 2) * 2];                                       \
        }                                                                           \
        /* compute KB from LDS B + register A (j-paired: 8 live B VGPRs) */         \
        _Pragma("unroll")                                                           \
        for (int ks = 0; ks < 4; ++ks) {                                            \
            bf16x8 a0, a1;                                                          \
            if constexpr (PRE) {                                                    \
                a0 = a[(CUR)][ks][0];                                               \
                a1 = a[(CUR)][ks][1];                                               \
            } else {                                                                \
                const int k = (KB) * BK + ks * 32 + quad * 8;                       \
                _Pragma("unroll")                                                   \
                for (int i = 0; i < 2; ++i) {                                       \
                    const float* px = xf + (size_t)(w * 32 + i * 16 + ln) * KK + k; \
                    const float4 f0 = *(const float4*)px;                           \
                    const float4 f1 = *(const float4*)(px + 4);                     \
                    uint4 ua;                                                       \
                    ua.x = pk_bf16_rtn(f0.x, f0.y);                                 \
                    ua.y = pk_bf16_rtn(f0.z, f0.w);                                 \
                    ua.z = pk_bf16_rtn(f1.x, f1.y);                                 \
                    ua.w = pk_bf16_rtn(f1.z, f1.w);                                 \
                    if (i == 0) a0 = *(bf16x8*)&ua; else a1 = *(bf16x8*)&ua;        \
                }                                                                   \
            }                                                                       \
            const int sl = lane ^ (ks << 1);                                        \
            _Pragma("unroll")                                                       \
            for (int jj = 0; jj < 4; jj += 2) {                                     \
                bf16x8 b0 = *(const bf16x8*)(sb + ((ks * 4 + jj) * 64 + sl) * 8);   \
                bf16x8 b1 = *(const bf16x8*)(sb + ((ks * 4 + jj + 1) * 64 + sl) * 8);\
                acc[0][jj]     = __builtin_amdgcn_mfma_f32_16x16x32_bf16(a0, b0, acc[0][jj], 0, 0, 0);     \
                acc[1][jj]     = __builtin_amdgcn_mfma_f32_16x16x32_bf16(a1, b0, acc[1][jj], 0, 0, 0);     \
                acc[0][jj + 1] = __builtin_amdgcn_mfma_f32_16x16x32_bf16(a0, b1, acc[0][jj + 1], 0, 0, 0); \
                acc[1][jj + 1] = __builtin_amdgcn_mfma_f32_16x16x32_bf16(a1, b1, acc[1][jj + 1], 0, 0, 0); \
            }                                                                       \
        }                                                                           \
        /* end-of-iter barrier: publishes buf[CUR^1] writes for iter KB+1 AND */    \
        /* protects buf[CUR] (read above) from iter KB+1's early write. */          \
        if ((KB) + 1 < NKB) barrier_nodrain();                                      \
    }

template <bool PRE>
__global__ __launch_bounds__(1024, 4) void qlin_gemm(
    const float* __restrict__ xf,               // fp32 x (fallback path)
    const unsigned short* __restrict__ xp,      // packed bf16 x (prepass path)
    const int* __restrict__ qw,                 // int32 [16384,4096]
    const float* __restrict__ scales,           // fp32 [16384,64]
    const float* __restrict__ bias,             // fp32 [16384]
    float* __restrict__ out)                    // fp32 [512,16384]
{
    __shared__ unsigned short sB[2][BN * BK];   // fragment-ordered + swizzled, 2 x 16 KB

    const int t    = threadIdx.x;
    const int lane = t & 63;
    const int w    = t >> 6;          // wave 0..15 -> M strip [w*32, w*32+32)
    const int ln   = lane & 15;
    const int quad = lane >> 4;
    const int n0   = blockIdx.x * BN;

    // ---- producer mapping: thread t -> qw row (t>>4), k-octet (t&15) ----
    const int r    = t >> 4;          // 0..63
    const int oct  = t & 15;
    const int ksp  = oct >> 2;        // frag k-slice 0..3
    const int jp   = r >> 4;          // frag col-tile 0..3
    const int ldst = (((oct & 3) << 4) | (r & 15)) ^ (ksp << 1);   // swizzled frag lane
    const int woff = ((ksp * 4 + jp) * 64 + ldst) * 8;
    const int* qp  = qw + (size_t)(n0 + r) * KK + oct * 8;
    const float* sp = scales + (size_t)(n0 + r) * 64 + (oct >> 3);

    floatx4 acc[2][4];
#pragma unroll
    for (int i = 0; i < 2; ++i)
#pragma unroll
        for (int j = 0; j < 4; ++j)
            acc[i][j] = (floatx4)0.0f;

    // ---- prologue ----
    // slab 0 qw stream first, then A(0): A(0) queues behind it only once
    // (pipeline fill); dequant waits the front of the queue.
    int4 qv0 = *(const int4*)(qp);
    int4 qv1 = *(const int4*)(qp + 4);
    float s  = sp[0];

    bf16x8 a[2][4][2];   // [buf][ks][i] -- A register double-buffer
    if constexpr (PRE) {
#pragma unroll
        for (int ks = 0; ks < 4; ++ks) {
            const unsigned short* ap = xp + (size_t)((ks * 32 + w * 2) * 64 + lane) * 8;
            a[0][ks][0] = *(const bf16x8*)(ap);
            a[0][ks][1] = *(const bf16x8*)(ap + 512);
        }
    }
    {   // dequant slab 0 straight into buf0 (waits qv slab 0 arrival)
        uint4 u = deq8(qv0, qv1, s);
        *(uint4*)(sB[0] + woff) = u;
    }
    // slab 1 qw in flight across the barrier
    qv0 = *(const int4*)(qp + BK);
    qv1 = *(const int4*)(qp + BK + 4);
    s   = sp[2];
    barrier_nodrain();

    // ---- main loop: hand-expanded 2x (static CUR, no unroll pragma) ----
    for (int kb = 0; kb < NKB; kb += 2) {
        GEMM_ITER(kb, 0)
        GEMM_ITER(kb + 1, 1)
    }

    // ---- epilogue: + bias, store fp32 ----
#pragma unroll
    for (int j = 0; j < 4; ++j) {
        const int n = n0 + j * 16 + ln;
        const float bv = bias[n];
#pragma unroll
        for (int i = 0; i < 2; ++i) {
            const int mbase = w * 32 + i * 16 + quad * 4;
#pragma unroll
            for (int rr = 0; rr < 4; ++rr)
                out[(size_t)(mbase + rr) * NN + n] = acc[i][j][rr] + bv;
        }
    }
}

extern "C" void kernel_launch(void* const* d_in, const int* in_sizes, int n_in,
                              void* d_out, int out_size, void* d_ws, size_t ws_size,
                              hipStream_t stream) {
    const float* x    = (const float*)d_in[0];
    const int* qw     = (const int*)d_in[1];
    const float* scl  = (const float*)d_in[2];
    const float* bias = (const float*)d_in[3];
    float* out        = (float*)d_out;

    dim3 grid(NN / BN);    // 256 blocks: one 64-col slab each, all 512 rows
    dim3 block(1024);      // 16 waves

    if (ws_size >= (size_t)MM * KK * sizeof(unsigned short)) {
        unsigned short* xp = (unsigned short*)d_ws;
        pack_x<<<dim3(MM * KK / (256 * 8)), dim3(256), 0, stream>>>(x, xp);
        qlin_gemm<true><<<grid, block, 0, stream>>>(x, xp, qw, scl, bias, out);
    } else {
        qlin_gemm<false><<<grid, block, 0, stream>>>(x, nullptr, qw, scl, bias, out);
    }
}